// Round 10
// baseline (102.934 us; speedup 1.0000x reference)
//
#include <hip/hip_runtime.h>

#define Bn 4
#define Cn 64
#define Hn 64
#define Wn 64
#define TW 8    // pixels (w) per block
#define F1n 5
#define F2n 10

typedef _Float16 half4v __attribute__((ext_vector_type(4)));
typedef _Float16 half8v __attribute__((ext_vector_type(8)));
typedef float    f32x4  __attribute__((ext_vector_type(4)));

#define MROW 20   // halves per M row (10 data, 10..15 zero for K-pad, 16..19 unused; 40B)

__global__ __launch_bounds__(256, 4) void cam_fused_kernel(
    const float* __restrict__ x, const float* __restrict__ pv,
    const float* __restrict__ w1, const float* __restrict__ b1,
    const float* __restrict__ w2, const float* __restrict__ b2,
    float* __restrict__ out)
{
    // LDS (~30.3 KB)
    __shared__ __align__(16) float xs[64 * 61];              // [c][5][12], stride 61
    __shared__ __align__(16) unsigned MhU[4][64 * (MROW/2)]; // per-wave scrambled M, f16
    __shared__ __align__(16) float pvt[TW * 64];             // pv tile [w][c]
    __shared__ __align__(16) float outs[64 * 12];            // [c][8] padded

    const int tid  = threadIdx.x;
    const int wave = tid >> 6;
    const int lane = tid & 63;        // = channel c
    const int g    = lane >> 4;       // 16-lane group (0..3)
    const int r16  = lane & 15;

    const int blk = blockIdx.x;       // 0..2047
    const int b   = blk >> 9;
    const int rem = blk & 511;
    const int h   = rem >> 3;
    const int w0  = (rem & 7) << 3;

    const int CHW = Cn * Hn * Wn;
    const int HW  = Hn * Wn;

    // ---- stage pv tile transposed: pvt[w][c] ----
    if (tid < 128) {
        const int c   = tid >> 1;
        const int seg = (tid & 1) << 2;
        const float4 v = *(const float4*)&pv[b * CHW + c * HW + h * Wn + w0 + seg];
        pvt[(seg + 0) * 64 + c] = v.x;
        pvt[(seg + 1) * 64 + c] = v.y;
        pvt[(seg + 2) * 64 + c] = v.z;
        pvt[(seg + 3) * 64 + c] = v.w;
    }

    // ---- stage x region: c 0..63, rows h-2..h+2, cols w0-2..w0+9 ----
    const float* xb = x + b * CHW;
    for (int idx = tid; idx < 64 * 60; idx += 256) {
        int c = idx / 60;
        int r = idx % 60;
        int i = r / 12, j = r % 12;
        int hh = h - 2 + i, ww = w0 - 2 + j;
        float v = 0.f;
        if ((unsigned)hh < 64u && (unsigned)ww < 64u)
            v = xb[c * HW + hh * Wn + ww];
        xs[c * 61 + i * 12 + j] = v;
    }

    // ---- one-time: zero K-pad halves 10..15 of each M row (u32 slots 5,6,7).
    //      Per-pixel scatter only writes halves 0..9, so this persists. ----
    {
        unsigned* row = &MhU[wave][lane * (MROW / 2)];
        row[5] = 0u; row[6] = 0u; row[7] = 0u;
    }
    __syncthreads();

    const float L2E = 1.4426950408889634f;

    // conv2 zero-pads its INPUT (conv1+relu output) at the border.
    const bool rOK0 = (h >= 1);
    const bool rOK2 = (h <= 62);

    // no __syncthreads() in this loop: MhU[wave] is wave-private; xs/pvt read-only.
    for (int pw = 0; pw < 2; ++pw) {
        const int lw = wave * 2 + pw;   // 0..7 within tile
        const int w  = w0 + lw;
        const bool cOK0 = (w >= 1);
        const bool cOK2 = (w <= 62);

        // ---- 5x5 patch from LDS ----
        float xp[5][5];
        #pragma unroll
        for (int i = 0; i < 5; ++i)
            #pragma unroll
            for (int j = 0; j < 5; ++j)
                xp[i][j] = xs[lane * 61 + i * 12 + lw + j];

        // ---- conv1+relu FEATURE-AT-A-TIME, folded into t2 immediately:
        //      live set = xp[25] + r1t[9] + t2[10] (~50 regs, fits the 64-VGPR
        //      partition; r1f[45] was the spill source). conv1 inner codegen
        //      is byte-identical to round 7 — only the fold point moved. ----
        float t2[F2n];
        #pragma unroll
        for (int gg = 0; gg < F2n; ++gg) t2[gg] = b2[gg];

        #pragma unroll
        for (int f = 0; f < F1n; ++f) {
            const float bias = b1[f];
            float r1t[9];
            #pragma unroll
            for (int ih = 0; ih < 3; ++ih) {
                const bool rok = (ih == 0) ? rOK0 : (ih == 2) ? rOK2 : true;
                #pragma unroll
                for (int iw = 0; iw < 3; ++iw) {
                    const bool cok = (iw == 0) ? cOK0 : (iw == 2) ? cOK2 : true;
                    float a = bias;
                    #pragma unroll
                    for (int i = 0; i < 3; ++i)
                        #pragma unroll
                        for (int j = 0; j < 3; ++j)
                            a = fmaf(xp[ih + i][iw + j], w1[f * 9 + i * 3 + j], a);
                    r1t[ih * 3 + iw] = (rok && cok) ? fmaxf(a, 0.f) : 0.f;
                }
            }
            #pragma unroll
            for (int gg = 0; gg < F2n; ++gg) {
                float a = t2[gg];
                #pragma unroll
                for (int q = 0; q < 9; ++q)
                    a = fmaf(r1t[q], w2[gg * 45 + f * 9 + q], a);
                t2[gg] = a;
            }
        }

        // ---- reshape-scramble scatter ([B,H,W,F,C]->[BHW,C,F] row-major):
        //      flat k = feature*64 + channel -> M[k/10][k%10], f16. ----
        {
            _Float16* Mh = (_Float16*)MhU[wave];
            #pragma unroll
            for (int gg = 0; gg < F2n; ++gg) {
                const int k = gg * 64 + lane;
                Mh[(k / 10) * MROW + (k % 10)] = (_Float16)t2[gg];
            }
        }

        // ---- fragments for mfma_f32_16x16x32_f16: lane holds row (l&15),
        //      k = 8*(l>>4)+j. Groups g>=2 own k=16..31 -> constant zero. ----
        const _Float16* Mh = (const _Float16*)MhU[wave];
        const int gc = g & 1;
        half8v fa[4];
        const half8v zf = { (_Float16)0, (_Float16)0, (_Float16)0, (_Float16)0,
                            (_Float16)0, (_Float16)0, (_Float16)0, (_Float16)0 };
        #pragma unroll
        for (int T = 0; T < 4; ++T) {
            const int base = (T * 16 + r16) * MROW + gc * 8;
            const half4v lo = *(const half4v*)&Mh[base];
            const half4v hi = *(const half4v*)&Mh[base + 4];
            const half8v f = __builtin_shufflevector(lo, hi, 0, 1, 2, 3, 4, 5, 6, 7);
            fa[T] = (g < 2) ? f : zf;
        }

        // pv at this lane's cols: pvf[R][j] = pv[16R + 4g + j]
        f32x4 pvf[4];
        #pragma unroll
        for (int R = 0; R < 4; ++R)
            pvf[R] = *(const f32x4*)&pvt[lw * 64 + R * 16 + g * 4];

        // ---- per-C streaming: 4 MFMAs -> immediate softmax+PV (acc live = 16).
        //      D layout (m89-verified): accC[R][j] at lane = E[16R+4g+j][16C+r16];
        //      symmetric read: lane owns row 16C+r16, cols {16R+4g+j}. ----
        float oval = 0.f;
        #pragma unroll
        for (int C = 0; C < 4; ++C) {
            f32x4 accC[4];
            #pragma unroll
            for (int R = 0; R < 4; ++R)
                accC[R] = __builtin_amdgcn_mfma_f32_16x16x32_f16(
                    fa[R], fa[C], (f32x4){0.f, 0.f, 0.f, 0.f}, 0, 0, 0);

            float mx = accC[0][0];
            #pragma unroll
            for (int R = 0; R < 4; ++R)
                #pragma unroll
                for (int j = 0; j < 4; ++j)
                    mx = fmaxf(mx, accC[R][j]);
            mx = fmaxf(mx, __shfl_xor(mx, 16));
            mx = fmaxf(mx, __shfl_xor(mx, 32));
            const float nm = -mx * L2E;
            float s = 0.f, d = 0.f;
            #pragma unroll
            for (int R = 0; R < 4; ++R) {
                float p0 = exp2f(fmaf(accC[R][0], L2E, nm));
                float p1 = exp2f(fmaf(accC[R][1], L2E, nm));
                float p2 = exp2f(fmaf(accC[R][2], L2E, nm));
                float p3 = exp2f(fmaf(accC[R][3], L2E, nm));
                s += (p0 + p1) + (p2 + p3);
                float dd = p0 * pvf[R][0];
                dd = fmaf(p1, pvf[R][1], dd);
                dd = fmaf(p2, pvf[R][2], dd);
                dd = fmaf(p3, pvf[R][3], dd);
                d += dd;
            }
            s += __shfl_xor(s, 16);
            s += __shfl_xor(s, 32);
            d += __shfl_xor(d, 16);
            d += __shfl_xor(d, 32);
            if (g == C) oval = d / s;   // kept row 16C + r16 == lane
        }
        outs[lane * 12 + lw] = oval;
    }

    __syncthreads();   // outs columns come from all waves

    // ---- coalesced output write: [64][8] tile -> out[b, c, h, w0..w0+7] ----
    if (tid < 128) {
        const int c   = tid >> 1;
        const int seg = (tid & 1) << 2;
        float4 v;
        v.x = outs[c * 12 + seg + 0];
        v.y = outs[c * 12 + seg + 1];
        v.z = outs[c * 12 + seg + 2];
        v.w = outs[c * 12 + seg + 3];
        *(float4*)&out[b * CHW + c * HW + h * Wn + w0 + seg] = v;
    }
}

extern "C" void kernel_launch(void* const* d_in, const int* in_sizes, int n_in,
                              void* d_out, int out_size, void* d_ws, size_t ws_size,
                              hipStream_t stream) {
    const float* x  = (const float*)d_in[0];
    const float* pv = (const float*)d_in[1];
    const float* w1 = (const float*)d_in[2];
    const float* b1 = (const float*)d_in[3];
    const float* w2 = (const float*)d_in[4];
    const float* b2 = (const float*)d_in[5];
    float* out = (float*)d_out;

    dim3 grid(Bn * Hn * (Wn / TW));   // 2048
    dim3 block(256);
    hipLaunchKernelGGL(cam_fused_kernel, grid, block, 0, stream,
                       x, pv, w1, b1, w2, b2, out);
}

// Round 11
// 88.121 us; speedup vs baseline: 1.1681x; 1.1681x over previous
//
#include <hip/hip_runtime.h>

#define Bn 4
#define Cn 64
#define Hn 64
#define Wn 64
#define TW 8    // pixels (w) per block
#define F1n 5
#define F2n 10

typedef _Float16 half4v __attribute__((ext_vector_type(4)));
typedef _Float16 half8v __attribute__((ext_vector_type(8)));
typedef float    f32x4  __attribute__((ext_vector_type(4)));

#define MROW 20   // halves per M row (10 data, 10..15 zero for K-pad, 16..19 unused; 40B)

// launch_bounds(256,3): 170-VGPR cap. The (256,4)/128-reg cap forced the conv
// live set (xp[25]+r1f[45]+t2[10]) out of registers (spill or LDS re-read);
// measured occupancy was ~3 blocks/CU regardless, so the cap bought nothing.
__global__ __launch_bounds__(256, 3) void cam_fused_kernel(
    const float* __restrict__ x, const float* __restrict__ pv,
    const float* __restrict__ w1, const float* __restrict__ b1,
    const float* __restrict__ w2, const float* __restrict__ b2,
    float* __restrict__ out)
{
    // LDS (~30.3 KB)
    __shared__ __align__(16) float xs[64 * 61];              // [c][5][12], stride 61
    __shared__ __align__(16) unsigned MhU[4][64 * (MROW/2)]; // per-wave scrambled M, f16
    __shared__ __align__(16) float pvt[TW * 64];             // pv tile [w][c]
    __shared__ __align__(16) float outs[64 * 12];            // [c][8] padded

    const int tid  = threadIdx.x;
    const int wave = tid >> 6;
    const int lane = tid & 63;        // = channel c
    const int g    = lane >> 4;       // 16-lane group (0..3)
    const int r16  = lane & 15;

    const int blk = blockIdx.x;       // 0..2047
    const int b   = blk >> 9;
    const int rem = blk & 511;
    const int h   = rem >> 3;
    const int w0  = (rem & 7) << 3;

    const int CHW = Cn * Hn * Wn;
    const int HW  = Hn * Wn;

    // ---- stage pv tile transposed: pvt[w][c] ----
    if (tid < 128) {
        const int c   = tid >> 1;
        const int seg = (tid & 1) << 2;
        const float4 v = *(const float4*)&pv[b * CHW + c * HW + h * Wn + w0 + seg];
        pvt[(seg + 0) * 64 + c] = v.x;
        pvt[(seg + 1) * 64 + c] = v.y;
        pvt[(seg + 2) * 64 + c] = v.z;
        pvt[(seg + 3) * 64 + c] = v.w;
    }

    // ---- stage x region: c 0..63, rows h-2..h+2, cols w0-2..w0+9 ----
    const float* xb = x + b * CHW;
    for (int idx = tid; idx < 64 * 60; idx += 256) {
        int c = idx / 60;
        int r = idx % 60;
        int i = r / 12, j = r % 12;
        int hh = h - 2 + i, ww = w0 - 2 + j;
        float v = 0.f;
        if ((unsigned)hh < 64u && (unsigned)ww < 64u)
            v = xb[c * HW + hh * Wn + ww];
        xs[c * 61 + i * 12 + j] = v;
    }

    // ---- one-time: zero K-pad halves 10..15 of each M row (u32 slots 5,6,7).
    //      Per-pixel scatter only writes halves 0..9, so this persists. ----
    {
        unsigned* row = &MhU[wave][lane * (MROW / 2)];
        row[5] = 0u; row[6] = 0u; row[7] = 0u;
    }
    __syncthreads();

    const float L2E = 1.4426950408889634f;

    // conv2 zero-pads its INPUT (conv1+relu output) at the border.
    const bool rOK0 = (h >= 1);
    const bool rOK2 = (h <= 62);

    // no __syncthreads() in this loop: MhU[wave] is wave-private; xs/pvt read-only.
    for (int pw = 0; pw < 2; ++pw) {
        const int lw = wave * 2 + pw;   // 0..7 within tile
        const int w  = w0 + lw;
        const bool cOK0 = (w >= 1);
        const bool cOK2 = (w <= 62);

        // ---- 5x5 patch from LDS ----
        float xp[5][5];
        #pragma unroll
        for (int i = 0; i < 5; ++i)
            #pragma unroll
            for (int j = 0; j < 5; ++j)
                xp[i][j] = xs[lane * 61 + i * 12 + lw + j];

        // ---- conv1 + relu, border-masked ----
        float r1f[45];
        #pragma unroll
        for (int f = 0; f < F1n; ++f) {
            const float bias = b1[f];
            #pragma unroll
            for (int ih = 0; ih < 3; ++ih) {
                const bool rok = (ih == 0) ? rOK0 : (ih == 2) ? rOK2 : true;
                #pragma unroll
                for (int iw = 0; iw < 3; ++iw) {
                    const bool cok = (iw == 0) ? cOK0 : (iw == 2) ? cOK2 : true;
                    float a = bias;
                    #pragma unroll
                    for (int i = 0; i < 3; ++i)
                        #pragma unroll
                        for (int j = 0; j < 3; ++j)
                            a = fmaf(xp[ih + i][iw + j], w1[f * 9 + i * 3 + j], a);
                    r1f[f * 9 + ih * 3 + iw] = (rok && cok) ? fmaxf(a, 0.f) : 0.f;
                }
            }
        }

        // ---- conv2 -> t2[10] ----
        float t2[F2n];
        #pragma unroll
        for (int gg = 0; gg < F2n; ++gg) {
            float a = b2[gg];
            #pragma unroll
            for (int q = 0; q < 45; ++q)
                a = fmaf(r1f[q], w2[gg * 45 + q], a);
            t2[gg] = a;
        }

        // ---- reshape-scramble scatter ([B,H,W,F,C]->[BHW,C,F] row-major):
        //      flat k = feature*64 + channel -> M[k/10][k%10], f16. ----
        {
            _Float16* Mh = (_Float16*)MhU[wave];
            #pragma unroll
            for (int gg = 0; gg < F2n; ++gg) {
                const int k = gg * 64 + lane;
                Mh[(k / 10) * MROW + (k % 10)] = (_Float16)t2[gg];
            }
        }

        // ---- fragments for mfma_f32_16x16x32_f16: lane holds row (l&15),
        //      k = 8*(l>>4)+j. Groups g>=2 own k=16..31 -> constant zero. ----
        const _Float16* Mh = (const _Float16*)MhU[wave];
        const int gc = g & 1;
        half8v fa[4];
        const half8v zf = { (_Float16)0, (_Float16)0, (_Float16)0, (_Float16)0,
                            (_Float16)0, (_Float16)0, (_Float16)0, (_Float16)0 };
        #pragma unroll
        for (int T = 0; T < 4; ++T) {
            const int base = (T * 16 + r16) * MROW + gc * 8;
            const half4v lo = *(const half4v*)&Mh[base];
            const half4v hi = *(const half4v*)&Mh[base + 4];
            const half8v f = __builtin_shufflevector(lo, hi, 0, 1, 2, 3, 4, 5, 6, 7);
            fa[T] = (g < 2) ? f : zf;
        }

        // pv at this lane's cols: pvf[R][j] = pv[16R + 4g + j]
        f32x4 pvf[4];
        #pragma unroll
        for (int R = 0; R < 4; ++R)
            pvf[R] = *(const f32x4*)&pvt[lw * 64 + R * 16 + g * 4];

        // ---- per-C streaming: 4 MFMAs -> immediate softmax+PV (acc live = 16).
        //      D layout (m89-verified): accC[R][j] at lane = E[16R+4g+j][16C+r16];
        //      symmetric read: lane owns row 16C+r16, cols {16R+4g+j}. ----
        float oval = 0.f;
        #pragma unroll
        for (int C = 0; C < 4; ++C) {
            f32x4 accC[4];
            #pragma unroll
            for (int R = 0; R < 4; ++R)
                accC[R] = __builtin_amdgcn_mfma_f32_16x16x32_f16(
                    fa[R], fa[C], (f32x4){0.f, 0.f, 0.f, 0.f}, 0, 0, 0);

            float mx = accC[0][0];
            #pragma unroll
            for (int R = 0; R < 4; ++R)
                #pragma unroll
                for (int j = 0; j < 4; ++j)
                    mx = fmaxf(mx, accC[R][j]);
            mx = fmaxf(mx, __shfl_xor(mx, 16));
            mx = fmaxf(mx, __shfl_xor(mx, 32));
            const float nm = -mx * L2E;
            float s = 0.f, d = 0.f;
            #pragma unroll
            for (int R = 0; R < 4; ++R) {
                float p0 = exp2f(fmaf(accC[R][0], L2E, nm));
                float p1 = exp2f(fmaf(accC[R][1], L2E, nm));
                float p2 = exp2f(fmaf(accC[R][2], L2E, nm));
                float p3 = exp2f(fmaf(accC[R][3], L2E, nm));
                s += (p0 + p1) + (p2 + p3);
                float dd = p0 * pvf[R][0];
                dd = fmaf(p1, pvf[R][1], dd);
                dd = fmaf(p2, pvf[R][2], dd);
                dd = fmaf(p3, pvf[R][3], dd);
                d += dd;
            }
            s += __shfl_xor(s, 16);
            s += __shfl_xor(s, 32);
            d += __shfl_xor(d, 16);
            d += __shfl_xor(d, 32);
            if (g == C) oval = d / s;   // kept row 16C + r16 == lane
        }
        outs[lane * 12 + lw] = oval;
    }

    __syncthreads();   // outs columns come from all waves

    // ---- coalesced output write: [64][8] tile -> out[b, c, h, w0..w0+7] ----
    if (tid < 128) {
        const int c   = tid >> 1;
        const int seg = (tid & 1) << 2;
        float4 v;
        v.x = outs[c * 12 + seg + 0];
        v.y = outs[c * 12 + seg + 1];
        v.z = outs[c * 12 + seg + 2];
        v.w = outs[c * 12 + seg + 3];
        *(float4*)&out[b * CHW + c * HW + h * Wn + w0 + seg] = v;
    }
}

extern "C" void kernel_launch(void* const* d_in, const int* in_sizes, int n_in,
                              void* d_out, int out_size, void* d_ws, size_t ws_size,
                              hipStream_t stream) {
    const float* x  = (const float*)d_in[0];
    const float* pv = (const float*)d_in[1];
    const float* w1 = (const float*)d_in[2];
    const float* b1 = (const float*)d_in[3];
    const float* w2 = (const float*)d_in[4];
    const float* b2 = (const float*)d_in[5];
    float* out = (float*)d_out;

    dim3 grid(Bn * Hn * (Wn / TW));   // 2048
    dim3 block(256);
    hipLaunchKernelGGL(cam_fused_kernel, grid, block, 0, stream,
                       x, pv, w1, b1, w2, b2, out);
}

// Round 12
// 62.757 us; speedup vs baseline: 1.6402x; 1.4042x over previous
//
#include <hip/hip_runtime.h>

#define Bn 4
#define Cn 64
#define Hn 64
#define Wn 64
#define TW 4    // pixels (w) per block; ONE pixel per wave
#define F1n 5
#define F2n 10

typedef _Float16 half4v __attribute__((ext_vector_type(4)));
typedef _Float16 half8v __attribute__((ext_vector_type(8)));
typedef float    f32x4  __attribute__((ext_vector_type(4)));

#define MROW 20   // halves per M row (10 data, 10..15 zero for K-pad, 16..19 unused; 40B)

// TW=4 / 1 px per wave: LDS ~24 KB -> 5-6 blocks/CU (20-24 waves/CU vs 12 at
// TW=8). Occupancy experiment: inner math identical to the 88 µs r11 kernel.
__global__ __launch_bounds__(256, 5) void cam_fused_kernel(
    const float* __restrict__ x, const float* __restrict__ pv,
    const float* __restrict__ w1, const float* __restrict__ b1,
    const float* __restrict__ w2, const float* __restrict__ b2,
    float* __restrict__ out)
{
    // LDS (~23.9 KB)
    __shared__ __align__(16) float xs[64 * 41];              // [c][5][8], stride 41
    __shared__ __align__(16) unsigned MhU[4][64 * (MROW/2)]; // per-wave scrambled M, f16
    __shared__ __align__(16) float pvt[TW * 64];             // pv tile [w][c]
    __shared__ __align__(16) float outs[64 * 5];             // [c][4] stride 5 (conflict-free)

    const int tid  = threadIdx.x;
    const int wave = tid >> 6;
    const int lane = tid & 63;        // = channel c
    const int g    = lane >> 4;       // 16-lane group (0..3)
    const int r16  = lane & 15;

    const int blk = blockIdx.x;       // 0..4095
    const int b   = blk >> 10;
    const int rem = blk & 1023;
    const int h   = rem >> 4;
    const int w0  = (rem & 15) << 2;

    const int CHW = Cn * Hn * Wn;
    const int HW  = Hn * Wn;

    // ---- stage pv tile transposed: pvt[w][c] ----
    if (tid < 64) {
        const float4 v = *(const float4*)&pv[b * CHW + tid * HW + h * Wn + w0];
        pvt[0 * 64 + tid] = v.x;
        pvt[1 * 64 + tid] = v.y;
        pvt[2 * 64 + tid] = v.z;
        pvt[3 * 64 + tid] = v.w;
    }

    // ---- stage x region: c 0..63, rows h-2..h+2, cols w0-2..w0+5 ----
    const float* xb = x + b * CHW;
    for (int idx = tid; idx < 64 * 40; idx += 256) {
        int c = idx / 40;
        int r = idx % 40;
        int i = r >> 3, j = r & 7;
        int hh = h - 2 + i, ww = w0 - 2 + j;
        float v = 0.f;
        if ((unsigned)hh < 64u && (unsigned)ww < 64u)
            v = xb[c * HW + hh * Wn + ww];
        xs[c * 41 + i * 8 + j] = v;
    }

    // ---- one-time: zero K-pad halves 10..15 of each M row (u32 slots 5,6,7) ----
    {
        unsigned* row = &MhU[wave][lane * (MROW / 2)];
        row[5] = 0u; row[6] = 0u; row[7] = 0u;
    }
    __syncthreads();

    const float L2E = 1.4426950408889634f;

    // conv2 zero-pads its INPUT (conv1+relu output) at the border.
    const bool rOK0 = (h >= 1);
    const bool rOK2 = (h <= 62);

    const int lw = wave;            // this wave's pixel (0..3)
    const int w  = w0 + lw;
    const bool cOK0 = (w >= 1);
    const bool cOK2 = (w <= 62);

    // ---- 5x5 patch from LDS ----
    float xp[5][5];
    #pragma unroll
    for (int i = 0; i < 5; ++i)
        #pragma unroll
        for (int j = 0; j < 5; ++j)
            xp[i][j] = xs[lane * 41 + i * 8 + lw + j];

    // ---- conv1 + relu, border-masked; weights via uniform s_load ----
    float r1f[45];
    #pragma unroll
    for (int f = 0; f < F1n; ++f) {
        const float bias = b1[f];
        #pragma unroll
        for (int ih = 0; ih < 3; ++ih) {
            const bool rok = (ih == 0) ? rOK0 : (ih == 2) ? rOK2 : true;
            #pragma unroll
            for (int iw = 0; iw < 3; ++iw) {
                const bool cok = (iw == 0) ? cOK0 : (iw == 2) ? cOK2 : true;
                float a = bias;
                #pragma unroll
                for (int i = 0; i < 3; ++i)
                    #pragma unroll
                    for (int j = 0; j < 3; ++j)
                        a = fmaf(xp[ih + i][iw + j], w1[f * 9 + i * 3 + j], a);
                r1f[f * 9 + ih * 3 + iw] = (rok && cok) ? fmaxf(a, 0.f) : 0.f;
            }
        }
    }

    // ---- conv2 -> t2[10] ----
    float t2[F2n];
    #pragma unroll
    for (int gg = 0; gg < F2n; ++gg) {
        float a = b2[gg];
        #pragma unroll
        for (int q = 0; q < 45; ++q)
            a = fmaf(r1f[q], w2[gg * 45 + q], a);
        t2[gg] = a;
    }

    // ---- reshape-scramble scatter ([B,H,W,F,C]->[BHW,C,F] row-major):
    //      flat k = feature*64 + channel -> M[k/10][k%10], f16. ----
    {
        _Float16* Mh = (_Float16*)MhU[wave];
        #pragma unroll
        for (int gg = 0; gg < F2n; ++gg) {
            const int k = gg * 64 + lane;
            Mh[(k / 10) * MROW + (k % 10)] = (_Float16)t2[gg];
        }
    }

    // ---- fragments for mfma_f32_16x16x32_f16: lane holds row (l&15),
    //      k = 8*(l>>4)+j. Groups g>=2 own k=16..31 -> constant zero. ----
    const _Float16* Mh = (const _Float16*)MhU[wave];
    const int gc = g & 1;
    half8v fa[4];
    const half8v zf = { (_Float16)0, (_Float16)0, (_Float16)0, (_Float16)0,
                        (_Float16)0, (_Float16)0, (_Float16)0, (_Float16)0 };
    #pragma unroll
    for (int T = 0; T < 4; ++T) {
        const int base = (T * 16 + r16) * MROW + gc * 8;
        const half4v lo = *(const half4v*)&Mh[base];
        const half4v hi = *(const half4v*)&Mh[base + 4];
        const half8v f = __builtin_shufflevector(lo, hi, 0, 1, 2, 3, 4, 5, 6, 7);
        fa[T] = (g < 2) ? f : zf;
    }

    // pv at this lane's cols: pvf[R][j] = pv[16R + 4g + j]
    f32x4 pvf[4];
    #pragma unroll
    for (int R = 0; R < 4; ++R)
        pvf[R] = *(const f32x4*)&pvt[lw * 64 + R * 16 + g * 4];

    // ---- per-C streaming: 4 MFMAs -> immediate softmax+PV (acc live = 16).
    //      D layout (m89-verified): accC[R][j] at lane = E[16R+4g+j][16C+r16];
    //      symmetric read: lane owns row 16C+r16, cols {16R+4g+j}. ----
    float oval = 0.f;
    #pragma unroll
    for (int C = 0; C < 4; ++C) {
        f32x4 accC[4];
        #pragma unroll
        for (int R = 0; R < 4; ++R)
            accC[R] = __builtin_amdgcn_mfma_f32_16x16x32_f16(
                fa[R], fa[C], (f32x4){0.f, 0.f, 0.f, 0.f}, 0, 0, 0);

        float mx = accC[0][0];
        #pragma unroll
        for (int R = 0; R < 4; ++R)
            #pragma unroll
            for (int j = 0; j < 4; ++j)
                mx = fmaxf(mx, accC[R][j]);
        mx = fmaxf(mx, __shfl_xor(mx, 16));
        mx = fmaxf(mx, __shfl_xor(mx, 32));
        const float nm = -mx * L2E;
        float s = 0.f, d = 0.f;
        #pragma unroll
        for (int R = 0; R < 4; ++R) {
            float p0 = exp2f(fmaf(accC[R][0], L2E, nm));
            float p1 = exp2f(fmaf(accC[R][1], L2E, nm));
            float p2 = exp2f(fmaf(accC[R][2], L2E, nm));
            float p3 = exp2f(fmaf(accC[R][3], L2E, nm));
            s += (p0 + p1) + (p2 + p3);
            float dd = p0 * pvf[R][0];
            dd = fmaf(p1, pvf[R][1], dd);
            dd = fmaf(p2, pvf[R][2], dd);
            dd = fmaf(p3, pvf[R][3], dd);
            d += dd;
        }
        s += __shfl_xor(s, 16);
        s += __shfl_xor(s, 32);
        d += __shfl_xor(d, 16);
        d += __shfl_xor(d, 32);
        if (g == C) oval = d / s;   // kept row 16C + r16 == lane
    }
    outs[lane * 5 + lw] = oval;

    __syncthreads();   // outs columns come from all waves

    // ---- output write: [64][4] tile -> out[b, c, h, w0..w0+3] ----
    if (tid < 64) {
        float4 v;
        v.x = outs[tid * 5 + 0];
        v.y = outs[tid * 5 + 1];
        v.z = outs[tid * 5 + 2];
        v.w = outs[tid * 5 + 3];
        *(float4*)&out[b * CHW + tid * HW + h * Wn + w0] = v;
    }
}

extern "C" void kernel_launch(void* const* d_in, const int* in_sizes, int n_in,
                              void* d_out, int out_size, void* d_ws, size_t ws_size,
                              hipStream_t stream) {
    const float* x  = (const float*)d_in[0];
    const float* pv = (const float*)d_in[1];
    const float* w1 = (const float*)d_in[2];
    const float* b1 = (const float*)d_in[3];
    const float* w2 = (const float*)d_in[4];
    const float* b2 = (const float*)d_in[5];
    float* out = (float*)d_out;

    dim3 grid(Bn * Hn * (Wn / TW));   // 4096
    dim3 block(256);
    hipLaunchKernelGGL(cam_fused_kernel, grid, block, 0, stream,
                       x, pv, w1, b1, w2, b2, out);
}